// Round 9
// baseline (261.549 us; speedup 1.0000x reference)
//
#include <hip/hip_runtime.h>
#include <hip/hip_bf16.h>

using bf16 = __hip_bfloat16;

typedef __bf16 bf16x8 __attribute__((ext_vector_type(8)));
typedef __bf16 bf16x4v __attribute__((ext_vector_type(4)));
typedef float  float4v __attribute__((ext_vector_type(4)));

#define MFMA16x16x32(a, b, c) __builtin_amdgcn_mfma_f32_16x16x32_bf16((a), (b), (c), 0, 0, 0)

#if __has_builtin(__builtin_amdgcn_exp2f)
#define EXP2F(x) __builtin_amdgcn_exp2f(x)
#else
#define EXP2F(x) exp2f(x)
#endif

#define T_SEQ 2048
#define NHEAD 16
#define CDIM  1024
#define HD3   3072

// async global->LDS, 16B per lane. LDS dest must be wave-uniform base + lane*16.
__device__ __forceinline__ void async_copy16(const void* g, void* l) {
    __builtin_amdgcn_global_load_lds(
        (__attribute__((address_space(1))) unsigned int*)g,
        (__attribute__((address_space(3))) unsigned int*)l,
        16, 0, 0);
}

// ---------------------------------------------------------------------------
// Runtime dtype probe: flag=1 -> fp32 inputs, 0 -> bf16.
// ---------------------------------------------------------------------------
__global__ __launch_bounds__(256) void detect_dtype_kernel(
    const unsigned short* __restrict__ xs, int* __restrict__ flag)
{
    __shared__ int red[256];
    int cnt = 0;
    for (int i = threadIdx.x; i < 65536; i += 256) {
        const unsigned short u = xs[i];
        const int e = (u >> 7) & 0xFF;
        if (e == 0xFF || (e != 0 && e < 0x60)) cnt++;
    }
    red[threadIdx.x] = cnt;
    __syncthreads();
    for (int s = 128; s > 0; s >>= 1) {
        if (threadIdx.x < s) red[threadIdx.x] += red[threadIdx.x + s];
        __syncthreads();
    }
    if (threadIdx.x == 0) flag[0] = (red[0] > 100) ? 1 : 0;
}

__global__ __launch_bounds__(256) void convert_f32_kernel(
    const float* __restrict__ x, const float* __restrict__ wa,
    const float* __restrict__ wp,
    bf16* __restrict__ xb, bf16* __restrict__ wab, bf16* __restrict__ wpb,
    const int* __restrict__ flag)
{
    if (flag[0] == 0) return;
    const int stride = gridDim.x * 256;
    for (int i = blockIdx.x * 256 + threadIdx.x; i < 8388608; i += stride) {
        if (i < 4194304)      xb[i] = __float2bfloat16(x[i]);
        else if (i < 7340032) wab[i - 4194304] = __float2bfloat16(wa[i - 4194304]);
        else                  wpb[i - 7340032] = __float2bfloat16(wp[i - 7340032]);
    }
}

// ---------------------------------------------------------------------------
// NT GEMM, BK=64, XOR-swizzled async staging. C[m,n]=sum_k A[m,k]B[n,k]+bias.
// scale_q: multiply (acc+bias) by 0.125*log2e for cols < 1024 (q-columns),
// pre-folding the attention softmax scale into the qkv projection.
// ---------------------------------------------------------------------------
__global__ __launch_bounds__(256) void gemm_nt_lds(
    const void* __restrict__ Araw, const bf16* __restrict__ Aconv,
    const void* __restrict__ Braw, const bf16* __restrict__ Bconv,
    const void* __restrict__ biasraw, void* __restrict__ Cv,
    int M, int N, int K, const int* __restrict__ flag, int is_final, int scale_q)
{
    const bool f32 = (flag[0] != 0);
    const bf16* A = f32 ? Aconv : (const bf16*)Araw;
    const bf16* B = f32 ? Bconv : (const bf16*)Braw;

    __shared__ bf16 As[128 * 64];
    __shared__ bf16 Bs[128 * 64];

    const int tid  = threadIdx.x;
    const int lane = tid & 63;
    const int wave = tid >> 6;
    const int wm = wave & 1, wn = wave >> 1;
    const int c = lane & 15, g = lane >> 4;

    const int bm = blockIdx.x * 128;
    const int bn = blockIdx.y * 128;

    const int srow = tid >> 3;
    const int slc  = ((tid & 7) ^ (srow & 7)) * 8;
    const bf16* gA = A + (size_t)(bm + srow) * K + slc;
    const bf16* gB = B + (size_t)(bn + srow) * K + slc;

    float4v acc[4][4] = {};

    for (int k0 = 0; k0 < K; k0 += 64) {
        __syncthreads();
#pragma unroll
        for (int q = 0; q < 4; ++q) {
            async_copy16(gA + k0 + (size_t)(q * 32) * K, As + q * 2048 + tid * 8);
            async_copy16(gB + k0 + (size_t)(q * 32) * K, Bs + q * 2048 + tid * 8);
        }
        __syncthreads();

#pragma unroll
        for (int kk = 0; kk < 2; ++kk) {
            bf16x8 af[4], bfr[4];
#pragma unroll
            for (int i = 0; i < 4; ++i) {
                af[i]  = *(const bf16x8*)&As[(wm * 64 + i * 16 + c) * 64 +
                                             (((kk * 4 + g) ^ (c & 7)) * 8)];
                bfr[i] = *(const bf16x8*)&Bs[(wn * 64 + i * 16 + c) * 64 +
                                             (((kk * 4 + g) ^ (c & 7)) * 8)];
            }
#pragma unroll
            for (int i = 0; i < 4; ++i)
#pragma unroll
                for (int j = 0; j < 4; ++j)
                    acc[i][j] = MFMA16x16x32(af[i], bfr[j], acc[i][j]);
        }
    }

    const bool f32o = is_final && f32;
    bf16*  Cb = (bf16*)Cv;
    float* Cf = (float*)Cv;

#pragma unroll
    for (int i = 0; i < 4; ++i) {
        const int row = bm + wm * 64 + i * 16 + g * 4;
#pragma unroll
        for (int j = 0; j < 4; ++j) {
            const int col = bn + wn * 64 + j * 16 + c;
            const float bv = f32 ? ((const float*)biasraw)[col]
                                 : __bfloat162float(((const bf16*)biasraw)[col]);
            const float sc = (scale_q && col < 1024) ? 0.18033688f : 1.0f;
            if (f32o) {
#pragma unroll
                for (int t = 0; t < 4; ++t)
                    Cf[(size_t)(row + t) * N + col] = (acc[i][j][t] + bv) * sc;
            } else {
#pragma unroll
                for (int t = 0; t < 4; ++t)
                    Cb[(size_t)(row + t) * N + col] =
                        __float2bfloat16((acc[i][j][t] + bv) * sc);
            }
        }
    }
}

// ---------------------------------------------------------------------------
// MFMA flash attention v4: S^T = K Q^T (Q pre-scaled in gemm1), O^T = V^T P,
// P in registers, l via ones-row MFMA. One q-tile per block; grid 512 (2
// blocks/CU); adjacent blocks are complementary (iters sum to 17) for
// balance under in-order dispatch.
// ---------------------------------------------------------------------------
__global__ __launch_bounds__(256) void attn_mfma(
    const bf16* __restrict__ qkv, bf16* __restrict__ y)
{
    __shared__ __bf16 Ks[2][128 * 64];   // [buf][key][dim], chunk ^ (key&7)
    __shared__ __bf16 Vt[2][64 * 128];   // [buf][dim][kappa], chunk ^ (dim&7)

    const int tid  = threadIdx.x;
    const int lane = tid & 63;
    const int w    = tid >> 6;
    const int c    = lane & 15;
    const int g    = lane >> 4;

    const int bx   = blockIdx.x;
    const int bh   = bx >> 4;            // 0..31
    const int j    = bx & 15;
    const int qblk = (j & 1) ? (j >> 1) : (15 - (j >> 1));  // adjacent sum: 17
    const int bb   = bh >> 4;
    const int h    = bh & 15;
    const size_t base = (size_t)bb * T_SEQ * HD3 + (size_t)h * 64;

    // staging indices
    const int krow = tid >> 3;                       // K: 0..31 (+ q*32)
    const int klc  = ((tid & 7) ^ (krow & 7)) * 8;   // K: logical dim col
    const int kq   = tid & 31;                       // V: key group
    const int dgv  = tid >> 5;                       // V: dim group 0..7
    const int vchunk = (kq >> 3) * 4 + (kq & 3);
    const int vlow   = ((kq >> 2) & 1) * 4;

    const bf16* kgbase = qkv + base + 1024;
    const bf16* vgbase = qkv + base + 2048;

    bf16x8 ones;
#pragma unroll
    for (int i = 0; i < 8; ++i) ones[i] = (__bf16)1.0f;

    const int q0 = qblk * 128;
    const int qw = q0 + w * 32;          // wave query origin

    // Q B-fragments (pre-scaled by 0.125*log2e in gemm1 epilogue)
    bf16x8 qf[2][2];
#pragma unroll
    for (int a = 0; a < 2; ++a)
#pragma unroll
        for (int kf2 = 0; kf2 < 2; ++kf2)
            qf[a][kf2] = *(const bf16x8*)(qkv + base
                + (size_t)(qw + a * 16 + c) * HD3 + kf2 * 32 + g * 8);

    float4v o[2][4] = {};
    float4v ol[2] = {};                  // lsum via ones-MFMA (rows identical)

    // ---- prologue: stage tile 0 into buf 0 ----
#pragma unroll
    for (int q = 0; q < 4; ++q)
        async_copy16(kgbase + (size_t)(q * 32 + krow) * HD3 + klc,
                     &Ks[0][q * 2048 + tid * 8]);
    {
        bf16x8 vr[4];
#pragma unroll
        for (int r = 0; r < 4; ++r)
            vr[r] = *(const bf16x8*)(vgbase + (size_t)(kq * 4 + r) * HD3 + dgv * 8);
#pragma unroll
        for (int jj = 0; jj < 8; ++jj) {
            const int d = dgv * 8 + jj;
            bf16x4v pk;
#pragma unroll
            for (int r = 0; r < 4; ++r) pk[r] = vr[r][jj];
            *(bf16x4v*)&Vt[0][d * 128 + ((vchunk ^ (d & 7)) << 3) + vlow] = pk;
        }
    }
    __syncthreads();

    int b = 0;
    for (int kt = 0; kt <= q0; kt += 128, b ^= 1) {
        const bool more = (kt + 128 <= q0);
        bf16x8 vr[4];
        if (more) {
#pragma unroll
            for (int q = 0; q < 4; ++q)
                async_copy16(kgbase + (size_t)(kt + 128 + q * 32 + krow) * HD3 + klc,
                             &Ks[b ^ 1][q * 2048 + tid * 8]);
#pragma unroll
            for (int r = 0; r < 4; ++r)
                vr[r] = *(const bf16x8*)(vgbase + (size_t)(kt + 128 + kq * 4 + r) * HD3 + dgv * 8);
        }

        bf16x8 pf[2][4];
#pragma unroll
        for (int hf = 0; hf < 2; ++hf) {
            // ---- S^T = K Q^T over 64 keys ----
            float4v sacc[2][4] = {};
#pragma unroll
            for (int jb = 0; jb < 4; ++jb) {
                const int key = hf * 64 + jb * 16 + c;
                bf16x8 a0 = *(const bf16x8*)&Ks[b][key * 64 + ((g ^ (c & 7)) * 8)];
                bf16x8 a1 = *(const bf16x8*)&Ks[b][key * 64 + (((4 + g) ^ (c & 7)) * 8)];
#pragma unroll
                for (int a = 0; a < 2; ++a) {
                    sacc[a][jb] = MFMA16x16x32(a0, qf[a][0], sacc[a][jb]);
                    sacc[a][jb] = MFMA16x16x32(a1, qf[a][1], sacc[a][jb]);
                }
            }
            // ---- mask + exp2 + pack P (registers only) ----
#pragma unroll
            for (int a = 0; a < 2; ++a) {
                const int qmin = qw + a * 16;
                if (kt + hf * 64 + 63 > qmin) {
                    const int query = qmin + c;
#pragma unroll
                    for (int jb = 0; jb < 4; ++jb) {
                        const int kb = kt + hf * 64 + jb * 16 + g * 4;
#pragma unroll
                        for (int t = 0; t < 4; ++t)
                            if (kb + t > query) sacc[a][jb][t] = -1e30f;
                    }
                }
#pragma unroll
                for (int jb = 0; jb < 4; ++jb)
#pragma unroll
                    for (int t = 0; t < 4; ++t)
                        sacc[a][jb][t] = EXP2F(sacc[a][jb][t]);
#pragma unroll
                for (int lkf = 0; lkf < 2; ++lkf) {
                    bf16x8 pk;
#pragma unroll
                    for (int jj = 0; jj < 8; ++jj)
                        pk[jj] = (__bf16)sacc[a][lkf * 2 + (jj >> 2)][jj & 3];
                    pf[a][hf * 2 + lkf] = pk;
                }
            }
        }

        // ---- O^T += V^T P ; lsum += 1^T P ----
#pragma unroll
        for (int kf = 0; kf < 4; ++kf) {
            ol[0] = MFMA16x16x32(ones, pf[0][kf], ol[0]);
            ol[1] = MFMA16x16x32(ones, pf[1][kf], ol[1]);
#pragma unroll
            for (int dn = 0; dn < 4; ++dn) {
                const int d = dn * 16 + c;
                bf16x8 vf = *(const bf16x8*)
                    &Vt[b][d * 128 + (((kf * 4 + g) ^ (d & 7)) << 3)];
                o[0][dn] = MFMA16x16x32(vf, pf[0][kf], o[0][dn]);
                o[1][dn] = MFMA16x16x32(vf, pf[1][kf], o[1][dn]);
            }
        }

        if (more) {
#pragma unroll
            for (int jj = 0; jj < 8; ++jj) {
                const int d = dgv * 8 + jj;
                bf16x4v pk;
#pragma unroll
                for (int r = 0; r < 4; ++r) pk[r] = vr[r][jj];
                *(bf16x4v*)&Vt[b ^ 1][d * 128 + ((vchunk ^ (d & 7)) << 3) + vlow] = pk;
            }
        }
        __syncthreads();
    }

    // ---- store: lane holds query q (col c), dims dn*16+g*4+t ----
#pragma unroll
    for (int a = 0; a < 2; ++a) {
        const float linv = 1.f / ol[a].x;
        const int q = qw + a * 16 + c;
        const size_t yb = ((size_t)bb * T_SEQ + q) * CDIM + h * 64;
#pragma unroll
        for (int dn = 0; dn < 4; ++dn) {
            bf16x4v ov;
#pragma unroll
            for (int t = 0; t < 4; ++t)
                ov[t] = (__bf16)(o[a][dn][t] * linv);
            *(bf16x4v*)&y[yb + dn * 16 + g * 4] = ov;
        }
    }
}

// ---------------------------------------------------------------------------
extern "C" void kernel_launch(void* const* d_in, const int* in_sizes, int n_in,
                              void* d_out, int out_size, void* d_ws, size_t ws_size,
                              hipStream_t stream)
{
    const int M = 4096;   // B*T
    char* ws = (char*)d_ws;

    int*  flag = (int*)ws;                        // 256 B
    bf16* xb   = (bf16*)(ws + 256);               // 8 MB
    bf16* wab  = (bf16*)(ws + 8388864);           // 6 MB
    bf16* wpb  = (bf16*)(ws + 14680320);          // 2 MB
    bf16* qkv  = (bf16*)(ws + 16777472);          // 25.2 MB
    bf16* yb   = (bf16*)(ws + 41943296);          // 8 MB

    detect_dtype_kernel<<<1, 256, 0, stream>>>((const unsigned short*)d_in[0], flag);

    convert_f32_kernel<<<2048, 256, 0, stream>>>(
        (const float*)d_in[0], (const float*)d_in[1], (const float*)d_in[3],
        xb, wab, wpb, flag);

    {   // qkv = x @ w_attn^T + b_attn  (q columns pre-scaled)
        dim3 grid(M / 128, 3072 / 128);
        gemm_nt_lds<<<grid, 256, 0, stream>>>(d_in[0], xb, d_in[1], wab,
                                              d_in[2], qkv, M, 3072, 1024, flag, 0, 1);
    }
    {   // flash attention (MFMA, register-P, 2 blocks/CU)
        attn_mfma<<<512, 256, 0, stream>>>(qkv, yb);
    }
    {   // out = y @ w_proj^T + b_proj
        dim3 grid(M / 128, 1024 / 128);
        gemm_nt_lds<<<grid, 256, 0, stream>>>(yb, yb, d_in[3], wpb,
                                              d_in[4], d_out, M, 1024, 1024, flag, 1, 0);
    }
    (void)in_sizes; (void)n_in; (void)out_size; (void)ws_size;
}

// Round 10
// 216.264 us; speedup vs baseline: 1.2094x; 1.2094x over previous
//
#include <hip/hip_runtime.h>
#include <hip/hip_bf16.h>

using bf16 = __hip_bfloat16;

typedef __bf16 bf16x8 __attribute__((ext_vector_type(8)));
typedef __bf16 bf16x4v __attribute__((ext_vector_type(4)));
typedef float  float4v __attribute__((ext_vector_type(4)));

#define MFMA16x16x32(a, b, c) __builtin_amdgcn_mfma_f32_16x16x32_bf16((a), (b), (c), 0, 0, 0)

#if __has_builtin(__builtin_amdgcn_exp2f)
#define EXP2F(x) __builtin_amdgcn_exp2f(x)
#else
#define EXP2F(x) exp2f(x)
#endif

#define T_SEQ 2048
#define NHEAD 16
#define CDIM  1024
#define HD3   3072

// async global->LDS, 16B per lane. LDS dest must be wave-uniform base + lane*16.
__device__ __forceinline__ void async_copy16(const void* g, void* l) {
    __builtin_amdgcn_global_load_lds(
        (__attribute__((address_space(1))) unsigned int*)g,
        (__attribute__((address_space(3))) unsigned int*)l,
        16, 0, 0);
}

// ---------------------------------------------------------------------------
// Runtime dtype probe: flag=1 -> fp32 inputs, 0 -> bf16.
// ---------------------------------------------------------------------------
__global__ __launch_bounds__(256) void detect_dtype_kernel(
    const unsigned short* __restrict__ xs, int* __restrict__ flag)
{
    __shared__ int red[256];
    int cnt = 0;
    for (int i = threadIdx.x; i < 16384; i += 256) {
        const unsigned short u = xs[i];
        const int e = (u >> 7) & 0xFF;
        if (e == 0xFF || (e != 0 && e < 0x60)) cnt++;
    }
    red[threadIdx.x] = cnt;
    __syncthreads();
    for (int s = 128; s > 0; s >>= 1) {
        if (threadIdx.x < s) red[threadIdx.x] += red[threadIdx.x + s];
        __syncthreads();
    }
    if (threadIdx.x == 0) flag[0] = (red[0] > 100) ? 1 : 0;
}

__global__ __launch_bounds__(256) void convert_f32_kernel(
    const float* __restrict__ x, const float* __restrict__ wa,
    const float* __restrict__ wp,
    bf16* __restrict__ xb, bf16* __restrict__ wab, bf16* __restrict__ wpb,
    const int* __restrict__ flag)
{
    if (flag[0] == 0) return;
    const int stride = gridDim.x * 256;
    for (int i = blockIdx.x * 256 + threadIdx.x; i < 8388608; i += stride) {
        if (i < 4194304)      xb[i] = __float2bfloat16(x[i]);
        else if (i < 7340032) wab[i - 4194304] = __float2bfloat16(wa[i - 4194304]);
        else                  wpb[i - 7340032] = __float2bfloat16(wp[i - 7340032]);
    }
}

// ---------------------------------------------------------------------------
// NT GEMM, BK=64, XOR-swizzled async staging. C[m,n]=sum_k A[m,k]B[n,k]+bias.
// scale_q: multiply (acc+bias) by 0.125*log2e for cols < 1024 (q-columns).
// ---------------------------------------------------------------------------
__global__ __launch_bounds__(256) void gemm_nt_lds(
    const void* __restrict__ Araw, const bf16* __restrict__ Aconv,
    const void* __restrict__ Braw, const bf16* __restrict__ Bconv,
    const void* __restrict__ biasraw, void* __restrict__ Cv,
    int M, int N, int K, const int* __restrict__ flag, int is_final, int scale_q)
{
    const bool f32 = (flag[0] != 0);
    const bf16* A = f32 ? Aconv : (const bf16*)Araw;
    const bf16* B = f32 ? Bconv : (const bf16*)Braw;

    __shared__ bf16 As[128 * 64];
    __shared__ bf16 Bs[128 * 64];

    const int tid  = threadIdx.x;
    const int lane = tid & 63;
    const int wave = tid >> 6;
    const int wm = wave & 1, wn = wave >> 1;
    const int c = lane & 15, g = lane >> 4;

    const int bm = blockIdx.x * 128;
    const int bn = blockIdx.y * 128;

    const int srow = tid >> 3;
    const int slc  = ((tid & 7) ^ (srow & 7)) * 8;
    const bf16* gA = A + (size_t)(bm + srow) * K + slc;
    const bf16* gB = B + (size_t)(bn + srow) * K + slc;

    float4v acc[4][4] = {};

    for (int k0 = 0; k0 < K; k0 += 64) {
        __syncthreads();
#pragma unroll
        for (int q = 0; q < 4; ++q) {
            async_copy16(gA + k0 + (size_t)(q * 32) * K, As + q * 2048 + tid * 8);
            async_copy16(gB + k0 + (size_t)(q * 32) * K, Bs + q * 2048 + tid * 8);
        }
        __syncthreads();

#pragma unroll
        for (int kk = 0; kk < 2; ++kk) {
            bf16x8 af[4], bfr[4];
#pragma unroll
            for (int i = 0; i < 4; ++i) {
                af[i]  = *(const bf16x8*)&As[(wm * 64 + i * 16 + c) * 64 +
                                             (((kk * 4 + g) ^ (c & 7)) * 8)];
                bfr[i] = *(const bf16x8*)&Bs[(wn * 64 + i * 16 + c) * 64 +
                                             (((kk * 4 + g) ^ (c & 7)) * 8)];
            }
#pragma unroll
            for (int i = 0; i < 4; ++i)
#pragma unroll
                for (int j = 0; j < 4; ++j)
                    acc[i][j] = MFMA16x16x32(af[i], bfr[j], acc[i][j]);
        }
    }

    const bool f32o = is_final && f32;
    bf16*  Cb = (bf16*)Cv;
    float* Cf = (float*)Cv;

#pragma unroll
    for (int i = 0; i < 4; ++i) {
        const int row = bm + wm * 64 + i * 16 + g * 4;
#pragma unroll
        for (int j = 0; j < 4; ++j) {
            const int col = bn + wn * 64 + j * 16 + c;
            const float bv = f32 ? ((const float*)biasraw)[col]
                                 : __bfloat162float(((const bf16*)biasraw)[col]);
            const float sc = (scale_q && col < 1024) ? 0.18033688f : 1.0f;
            if (f32o) {
#pragma unroll
                for (int t = 0; t < 4; ++t)
                    Cf[(size_t)(row + t) * N + col] = (acc[i][j][t] + bv) * sc;
            } else {
#pragma unroll
                for (int t = 0; t < 4; ++t)
                    Cb[(size_t)(row + t) * N + col] =
                        __float2bfloat16((acc[i][j][t] + bv) * sc);
            }
        }
    }
}

// ---------------------------------------------------------------------------
// MFMA flash attention v5: S^T = K Q^T (Q pre-scaled), O^T = V^T P, P in
// registers, l via ones-MFMA. Dispatch-aware balance: blocks 0..255 take
// heavy q-tiles (15-(i&7)), blocks 256..511 take light (i&7) -> co-resident
// pairs (i, i+256) sum to 17 iters. Fully-masked 64-key halves are skipped
// (wave-uniform).
// ---------------------------------------------------------------------------
__global__ __launch_bounds__(256) void attn_mfma(
    const bf16* __restrict__ qkv, bf16* __restrict__ y)
{
    __shared__ __bf16 Ks[2][128 * 64];   // [buf][key][dim], chunk ^ (key&7)
    __shared__ __bf16 Vt[2][64 * 128];   // [buf][dim][kappa], chunk ^ (dim&7)

    const int tid  = threadIdx.x;
    const int lane = tid & 63;
    const int w    = tid >> 6;
    const int c    = lane & 15;
    const int g    = lane >> 4;

    const int i    = blockIdx.x;
    const int bh   = (i & 255) >> 3;     // 0..31 (batch*head)
    const int j    = i & 7;
    const int qblk = (i < 256) ? (15 - j) : j;
    const int bb   = bh >> 4;
    const int h    = bh & 15;
    const size_t base = (size_t)bb * T_SEQ * HD3 + (size_t)h * 64;

    // staging indices
    const int krow = tid >> 3;                       // K: 0..31 (+ q*32)
    const int klc  = ((tid & 7) ^ (krow & 7)) * 8;   // K: logical dim col
    const int kq   = tid & 31;                       // V: key group
    const int dgv  = tid >> 5;                       // V: dim group 0..7
    const int vchunk = (kq >> 3) * 4 + (kq & 3);
    const int vlow   = ((kq >> 2) & 1) * 4;

    const bf16* kgbase = qkv + base + 1024;
    const bf16* vgbase = qkv + base + 2048;

    bf16x8 ones;
#pragma unroll
    for (int ii = 0; ii < 8; ++ii) ones[ii] = (__bf16)1.0f;

    const int q0 = qblk * 128;
    const int qw = q0 + w * 32;          // wave query origin

    // Q B-fragments (pre-scaled by 0.125*log2e in gemm1 epilogue)
    bf16x8 qf[2][2];
#pragma unroll
    for (int a = 0; a < 2; ++a)
#pragma unroll
        for (int kf2 = 0; kf2 < 2; ++kf2)
            qf[a][kf2] = *(const bf16x8*)(qkv + base
                + (size_t)(qw + a * 16 + c) * HD3 + kf2 * 32 + g * 8);

    float4v o[2][4] = {};
    float4v ol[2] = {};                  // lsum via ones-MFMA

    // ---- prologue: stage tile 0 into buf 0 ----
#pragma unroll
    for (int q = 0; q < 4; ++q)
        async_copy16(kgbase + (size_t)(q * 32 + krow) * HD3 + klc,
                     &Ks[0][q * 2048 + tid * 8]);
    {
        bf16x8 vr[4];
#pragma unroll
        for (int r = 0; r < 4; ++r)
            vr[r] = *(const bf16x8*)(vgbase + (size_t)(kq * 4 + r) * HD3 + dgv * 8);
#pragma unroll
        for (int jj = 0; jj < 8; ++jj) {
            const int d = dgv * 8 + jj;
            bf16x4v pk;
#pragma unroll
            for (int r = 0; r < 4; ++r) pk[r] = vr[r][jj];
            *(bf16x4v*)&Vt[0][d * 128 + ((vchunk ^ (d & 7)) << 3) + vlow] = pk;
        }
    }
    __syncthreads();

    int b = 0;
    for (int kt = 0; kt <= q0; kt += 128, b ^= 1) {
        const bool more = (kt + 128 <= q0);
        bf16x8 vr[4];
        if (more) {
#pragma unroll
            for (int q = 0; q < 4; ++q)
                async_copy16(kgbase + (size_t)(kt + 128 + q * 32 + krow) * HD3 + klc,
                             &Ks[b ^ 1][q * 2048 + tid * 8]);
#pragma unroll
            for (int r = 0; r < 4; ++r)
                vr[r] = *(const bf16x8*)(vgbase + (size_t)(kt + 128 + kq * 4 + r) * HD3 + dgv * 8);
        }

#pragma unroll
        for (int hf = 0; hf < 2; ++hf) {
            if (kt + hf * 64 > qw + 31) continue;   // whole half masked for wave

            // ---- S^T = K Q^T over 64 keys ----
            float4v sacc[2][4] = {};
#pragma unroll
            for (int jb = 0; jb < 4; ++jb) {
                const int key = hf * 64 + jb * 16 + c;
                bf16x8 a0 = *(const bf16x8*)&Ks[b][key * 64 + ((g ^ (c & 7)) * 8)];
                bf16x8 a1 = *(const bf16x8*)&Ks[b][key * 64 + (((4 + g) ^ (c & 7)) * 8)];
#pragma unroll
                for (int a = 0; a < 2; ++a) {
                    sacc[a][jb] = MFMA16x16x32(a0, qf[a][0], sacc[a][jb]);
                    sacc[a][jb] = MFMA16x16x32(a1, qf[a][1], sacc[a][jb]);
                }
            }
            // ---- mask + exp2 + pack P (registers only) ----
            bf16x8 pf[2][2];
#pragma unroll
            for (int a = 0; a < 2; ++a) {
                const int qmin = qw + a * 16;
                if (kt + hf * 64 + 63 > qmin) {
                    const int query = qmin + c;
#pragma unroll
                    for (int jb = 0; jb < 4; ++jb) {
                        const int kb = kt + hf * 64 + jb * 16 + g * 4;
#pragma unroll
                        for (int t = 0; t < 4; ++t)
                            if (kb + t > query) sacc[a][jb][t] = -1e30f;
                    }
                }
#pragma unroll
                for (int jb = 0; jb < 4; ++jb)
#pragma unroll
                    for (int t = 0; t < 4; ++t)
                        sacc[a][jb][t] = EXP2F(sacc[a][jb][t]);
#pragma unroll
                for (int lkf = 0; lkf < 2; ++lkf) {
                    bf16x8 pk;
#pragma unroll
                    for (int jj = 0; jj < 8; ++jj)
                        pk[jj] = (__bf16)sacc[a][lkf * 2 + (jj >> 2)][jj & 3];
                    pf[a][lkf] = pk;
                }
            }
            // ---- O^T += V^T P ; lsum += 1^T P (this half) ----
#pragma unroll
            for (int lkf = 0; lkf < 2; ++lkf) {
                const int kf = hf * 2 + lkf;
                ol[0] = MFMA16x16x32(ones, pf[0][lkf], ol[0]);
                ol[1] = MFMA16x16x32(ones, pf[1][lkf], ol[1]);
#pragma unroll
                for (int dn = 0; dn < 4; ++dn) {
                    const int d = dn * 16 + c;
                    bf16x8 vf = *(const bf16x8*)
                        &Vt[b][d * 128 + (((kf * 4 + g) ^ (d & 7)) << 3)];
                    o[0][dn] = MFMA16x16x32(vf, pf[0][lkf], o[0][dn]);
                    o[1][dn] = MFMA16x16x32(vf, pf[1][lkf], o[1][dn]);
                }
            }
        }

        if (more) {
#pragma unroll
            for (int jj = 0; jj < 8; ++jj) {
                const int d = dgv * 8 + jj;
                bf16x4v pk;
#pragma unroll
                for (int r = 0; r < 4; ++r) pk[r] = vr[r][jj];
                *(bf16x4v*)&Vt[b ^ 1][d * 128 + ((vchunk ^ (d & 7)) << 3) + vlow] = pk;
            }
        }
        __syncthreads();
    }

    // ---- store: lane holds query q (col c), dims dn*16+g*4+t ----
#pragma unroll
    for (int a = 0; a < 2; ++a) {
        const float linv = 1.f / ol[a].x;
        const int q = qw + a * 16 + c;
        const size_t yb = ((size_t)bb * T_SEQ + q) * CDIM + h * 64;
#pragma unroll
        for (int dn = 0; dn < 4; ++dn) {
            bf16x4v ov;
#pragma unroll
            for (int t = 0; t < 4; ++t)
                ov[t] = (__bf16)(o[a][dn][t] * linv);
            *(bf16x4v*)&y[yb + dn * 16 + g * 4] = ov;
        }
    }
}

// ---------------------------------------------------------------------------
extern "C" void kernel_launch(void* const* d_in, const int* in_sizes, int n_in,
                              void* d_out, int out_size, void* d_ws, size_t ws_size,
                              hipStream_t stream)
{
    const int M = 4096;   // B*T
    char* ws = (char*)d_ws;

    int*  flag = (int*)ws;                        // 256 B
    bf16* xb   = (bf16*)(ws + 256);               // 8 MB
    bf16* wab  = (bf16*)(ws + 8388864);           // 6 MB
    bf16* wpb  = (bf16*)(ws + 14680320);          // 2 MB
    bf16* qkv  = (bf16*)(ws + 16777472);          // 25.2 MB
    bf16* yb   = (bf16*)(ws + 41943296);          // 8 MB

    detect_dtype_kernel<<<1, 256, 0, stream>>>((const unsigned short*)d_in[0], flag);

    convert_f32_kernel<<<512, 256, 0, stream>>>(
        (const float*)d_in[0], (const float*)d_in[1], (const float*)d_in[3],
        xb, wab, wpb, flag);

    {   // qkv = x @ w_attn^T + b_attn  (q columns pre-scaled)
        dim3 grid(M / 128, 3072 / 128);
        gemm_nt_lds<<<grid, 256, 0, stream>>>(d_in[0], xb, d_in[1], wab,
                                              d_in[2], qkv, M, 3072, 1024, flag, 0, 1);
    }
    {   // flash attention (MFMA, dispatch-balanced)
        attn_mfma<<<512, 256, 0, stream>>>(qkv, yb);
    }
    {   // out = y @ w_proj^T + b_proj
        dim3 grid(M / 128, 1024 / 128);
        gemm_nt_lds<<<grid, 256, 0, stream>>>(yb, yb, d_in[3], wpb,
                                              d_in[4], d_out, M, 1024, 1024, flag, 1, 0);
    }
    (void)in_sizes; (void)n_in; (void)out_size; (void)ws_size;
}